// Round 8
// baseline (936.276 us; speedup 1.0000x reference)
//
#include <hip/hip_runtime.h>
#include <stdint.h>

typedef unsigned short u16;
typedef unsigned int u32;
typedef __attribute__((ext_vector_type(8))) __bf16 bf16x8;
typedef __attribute__((ext_vector_type(4))) float f32x4;
typedef __attribute__((ext_vector_type(4))) u32 u32x4;
typedef __attribute__((ext_vector_type(2))) u32 u32x2;
typedef __attribute__((ext_vector_type(4))) int i32x4;

#define DEV __device__ __forceinline__

constexpr int V = 5000, D = 300, H = 256, BB = 16, T = 512;
constexpr int M = BB * T;      // 8192
constexpr int DP = 320;        // D padded
constexpr int KP = 5024;       // V padded (E k-dim)
constexpr int G4 = 1024;       // 4H
constexpr int NPAD = 5120;     // V padded (out n-dim)
constexpr int NWRK = 128;      // worker WGs
constexpr int EMBS_ST = 328;   // embS row stride (u16)

// workspace layout (bytes). sync block replaces the old emb buffer.
constexpr size_t OFF_EB    = 0;                                   // bf16 [DP][KP]
constexpr size_t OFF_WXB   = OFF_EB    + (size_t)DP * KP * 2;     // bf16 [G4][DP]
constexpr size_t OFF_UHB   = OFF_WXB   + (size_t)G4 * DP * 2;     // i8 qU [G4][H] + f32 zsc[G4]
constexpr size_t OFF_WOUTB = OFF_UHB   + (size_t)G4 * H * 2;      // bf16 [NPAD][H]
constexpr size_t OFF_GATES = OFF_WOUTB + (size_t)NPAD * H * 2;    // bf16 [T][B][256][4]
constexpr size_t OFF_GALL  = OFF_GATES + (size_t)T * BB * G4 * 2; // bf16 [M][H]
constexpr size_t OFF_SYNC  = OFF_GALL  + (size_t)M * H * 2;       // u32 flag[16] + u32 prog[8]

DEV u16 f2bf(float f) {
  u32 i = __builtin_bit_cast(u32, f);
  return (u16)((i + 0x7FFFu + ((i >> 16) & 1u)) >> 16);
}
DEV float bf2f(u16 u) { return __builtin_bit_cast(float, (u32)u << 16); }
DEV f32x4 MFMA(u32x4 a, u32x4 b, f32x4 c) {
  return __builtin_amdgcn_mfma_f32_16x16x32_bf16(
      __builtin_bit_cast(bf16x8, a), __builtin_bit_cast(bf16x8, b), c, 0, 0, 0);
}
DEV i32x4 MFMA8(u32x4 a, u32x4 b, i32x4 c) {
  return __builtin_amdgcn_mfma_i32_16x16x64_i8(
      __builtin_bit_cast(i32x4, a), __builtin_bit_cast(i32x4, b), c, 0, 0, 0);
}
DEV float sigm(float x) { return 1.f / (1.f + __expf(-x)); }
DEV float tanh_s(float x) { float e = __expf(2.f * x); return 1.f - 2.f / (e + 1.f); }

DEV void bar_lds() {
  asm volatile("s_waitcnt lgkmcnt(0)" ::: "memory");
  __builtin_amdgcn_sched_barrier(0);
  __builtin_amdgcn_s_barrier();
  __builtin_amdgcn_sched_barrier(0);
}
DEV u32 ld32_cohere(const u32* p) {
  u32 v;
  asm volatile("global_load_dword %0, %1, off sc0 sc1\n\ts_waitcnt vmcnt(0)"
               : "=v"(v) : "v"(p) : "memory");
  return v;
}
DEV void st32_cohere(u32* p, u32 v) {
  asm volatile("global_store_dword %0, %1, off sc0 sc1" :: "v"(p), "v"(v) : "memory");
}
DEV u32x4 ld16_cohere(const void* p) {
  u32x4 v;
  asm volatile("global_load_dwordx4 %0, %1, off sc0 sc1" : "=v"(v) : "v"(p));
  return v;
}

// ---------------- K0: weight prep (fp32 -> padded bf16) + sync zero
__global__ __launch_bounds__(256) void k_prep(
    const float* __restrict__ E, const float* __restrict__ Wf, const float* __restrict__ Wg,
    const float* __restrict__ Wi, const float* __restrict__ Wo,
    const float* __restrict__ Wout, char* __restrict__ ws) {
  u16* Eb = (u16*)(ws + OFF_EB);
  u16* Wxb = (u16*)(ws + OFF_WXB);
  u16* Wob = (u16*)(ws + OFF_WOUTB);

  const int NE = DP * KP, NW = G4 * DP, NWO = NPAD * H;
  const int total = NE + NW + NWO + 32;
  for (int i = blockIdx.x * blockDim.x + threadIdx.x; i < total; i += gridDim.x * blockDim.x) {
    int j = i;
    if (j < NE) {
      int nn = j / KP, k = j % KP;
      Eb[j] = f2bf((nn < D && k < V) ? E[(size_t)nn * V + k] : 0.f);
      continue;
    }
    j -= NE;
    if (j < NW) {
      int r = j / DP, k = j % DP;
      const float* Wp = (r < 256) ? Wf : (r < 512) ? Wg : (r < 768) ? Wi : Wo;
      Wxb[j] = f2bf((k < D) ? Wp[(size_t)(r & 255) * D + k] : 0.f);
      continue;
    }
    j -= NW;
    if (j < NWO) {
      int nn = j / H, k = j % H;
      Wob[j] = f2bf((nn < V) ? Wout[(size_t)nn * H + k] : 0.f);
      continue;
    }
    j -= NWO;
    if (j < 32) ((u32*)(ws + OFF_SYNC))[j] = 0u;
  }
}

// ---------------- K0b: Uh -> int8 (per-row scale)
__global__ __launch_bounds__(256) void k_prep_u(
    const float* __restrict__ Uf, const float* __restrict__ Ug,
    const float* __restrict__ Ui, const float* __restrict__ Uo, char* __restrict__ ws) {
  char* qU = ws + OFF_UHB;
  float* zsc = (float*)(ws + OFF_UHB + (size_t)G4 * H);
  const int row = blockIdx.x * 4 + (threadIdx.x >> 6);
  const int lane = threadIdx.x & 63;
  const float* Up = (row < 256) ? Uf : (row < 512) ? Ug : (row < 768) ? Ui : Uo;
  f32x4 v = *(const f32x4*)(Up + (size_t)(row & 255) * H + lane * 4);
  float m = fmaxf(fmaxf(fabsf(v[0]), fabsf(v[1])), fmaxf(fabsf(v[2]), fabsf(v[3])));
  for (int i = 1; i < 64; i <<= 1) m = fmaxf(m, __shfl_xor(m, i));
  float inv = (m > 0.f) ? 127.f / m : 0.f;
  int q0 = (int)rintf(v[0] * inv), q1 = (int)rintf(v[1] * inv);
  int q2 = (int)rintf(v[2] * inv), q3 = (int)rintf(v[3] * inv);
  q0 = max(-127, min(127, q0)); q1 = max(-127, min(127, q1));
  q2 = max(-127, min(127, q2)); q3 = max(-127, min(127, q3));
  u32 pk = (u32)(q0 & 255) | ((u32)(q1 & 255) << 8) | ((u32)(q2 & 255) << 16) |
           ((u32)(q3 & 255) << 24);
  *(u32*)(qU + (size_t)row * H + lane * 4) = pk;
  if (lane == 0) zsc[row] = m / 16129.f;  // s_n / 127^2
}

// ---------------- mega-kernel: blocks 0..7 scan; blocks 8..135 workers (emb+gates, out)
__global__ __launch_bounds__(512) void k_fused(const float* __restrict__ x,
                                               const float* __restrict__ hidden,
                                               const float* __restrict__ ctx,
                                               char* __restrict__ ws,
                                               float* __restrict__ out) {
  __shared__ __align__(16) char smem[49152];  // union: scan 17.4KB | worker 48KB
  const int tid = threadIdx.x;
  const int lane = tid & 63, wv = tid >> 6;
  const int l15 = lane & 15, lc = lane >> 4;
  u32* flag = (u32*)(ws + OFF_SYNC);       // [16] per-32-step gates chunks
  u32* prog = (u32*)(ws + OFF_SYNC + 64);  // [8] scan progress per batch-pair

  if (blockIdx.x < 8) {
    // =========== SCAN ROLE (R7 structure + chunk gating + progress publish) ===========
    __builtin_amdgcn_s_setprio(1);
    const char* qU = (const char*)(ws + OFF_UHB);
    const float* zsc = (const float*)(ws + OFF_UHB + (size_t)G4 * H);
    const u16* gates = (const u16*)(ws + OFF_GATES);
    u16* gall = (u16*)(ws + OFF_GALL);
    char* pqp = smem;                  // [par][b][n] int8: idx (par*2+b)*256+n
    int* zwp = (int*)(smem + 1024);    // [par][wv][t8][b][16]

    const int g = blockIdx.x;
    u32x4 uq[4][2][4];
#pragma unroll
    for (int gg = 0; gg < 4; gg++)
#pragma unroll
      for (int j = 0; j < 2; j++)
#pragma unroll
        for (int kt = 0; kt < 4; kt++)
          uq[gg][j][kt] = *(const u32x4*)(
              qU + (size_t)(gg * 256 + wv * 32 + j * 16 + l15) * H + kt * 64 + lc * 16);

    const int b = lane >> 5, np = lane & 31;
    const int n = wv * 32 + np;
    const int jj = (np >> 4) & 1, rr = np & 15;
    const int b_glob = g * 2 + b;
    float c = ctx[n];
    const float zs0 = zsc[n], zs1 = zsc[n + 256], zs2 = zsc[n + 512], zs3 = zsc[n + 768];

    {  // h(0): scale 4/127
      const int b0 = tid >> 8, n0i = tid & 255;
      float h0 = hidden[n0i];
      h0 = fminf(3.999f, fmaxf(-3.999f, h0));
      pqp[(0 * 2 + b0) * 256 + n0i] = (char)(int)rintf(h0 * 31.75f);
    }
    // wait chunk 0 before first gx loads
    if (tid == 0) {
      while (ld32_cohere(&flag[0]) < 16u) __builtin_amdgcn_s_sleep(8);
    }
    __syncthreads();

    u32x2 gxc = *(const u32x2*)(gates + (((size_t)0 * 16 + b_glob) * 256 + n) * 4);
    u32x2 gxn = *(const u32x2*)(gates + (((size_t)1 * 16 + b_glob) * 256 + n) * 4);

#pragma unroll 1
    for (int t = 0; t < T; ++t) {
      const int par = t & 1;
      if (((t + 2) & 31) == 0 && (t + 2) < T) {  // gate prefetch of chunk (t+2)>>5
        const int ck = (t + 2) >> 5;
        if (tid == 0) {
          while (ld32_cohere(&flag[ck]) < 16u) __builtin_amdgcn_s_sleep(8);
        }
        bar_lds();
      }
      u32x4 bfr[4];
#pragma unroll
      for (int kt = 0; kt < 4; kt++)
        bfr[kt] = *(const u32x4*)&pqp[(par * 2 + (l15 & 1)) * 256 + kt * 64 + lc * 16];

      i32x4 acc[4][2];
#pragma unroll
      for (int gg = 0; gg < 4; gg++)
#pragma unroll
        for (int j = 0; j < 2; j++) {
          i32x4 a = {0, 0, 0, 0};
#pragma unroll
          for (int kt = 0; kt < 4; kt++) a = MFMA8(uq[gg][j][kt], bfr[kt], a);
          acc[gg][j] = a;
        }
      if (l15 < 2) {
#pragma unroll
        for (int gg = 0; gg < 4; gg++)
#pragma unroll
          for (int j = 0; j < 2; j++)
            *(i32x4*)&zwp[(((par * 8 + wv) * 8 + gg * 2 + j) * 2 + l15) * 16 + lc * 4] =
                acc[gg][j];
      }
      asm volatile("s_waitcnt lgkmcnt(0)" ::: "memory");
      __builtin_amdgcn_sched_barrier(0);

      const float hs = (t == 0) ? 4.f : 1.f;
      float z0 = (float)zwp[(((par * 8 + wv) * 8 + 0 + jj) * 2 + b) * 16 + rr] * (zs0 * hs) +
                 bf2f((u16)(gxc[0] & 0xFFFFu));
      float z1 = (float)zwp[(((par * 8 + wv) * 8 + 2 + jj) * 2 + b) * 16 + rr] * (zs1 * hs) +
                 bf2f((u16)(gxc[0] >> 16));
      float z2 = (float)zwp[(((par * 8 + wv) * 8 + 4 + jj) * 2 + b) * 16 + rr] * (zs2 * hs) +
                 bf2f((u16)(gxc[1] & 0xFFFFu));
      float z3 = (float)zwp[(((par * 8 + wv) * 8 + 6 + jj) * 2 + b) * 16 + rr] * (zs3 * hs) +
                 bf2f((u16)(gxc[1] >> 16));
      float fv = sigm(z0), gv = tanh_s(z1), iv = sigm(z2), ov = sigm(z3);
      c = gv * iv + c * fv;
      float hn = ov * tanh_s(c);
      gall[((size_t)b_glob * T + t) * H + n] = f2bf(gv);
      pqp[((par ^ 1) * 2 + b) * 256 + n] = (char)(int)rintf(hn * 127.f);
      gxc = gxn;
      int t2 = (t + 2 < T) ? (t + 2) : t;
      gxn = *(const u32x2*)(gates + (((size_t)t2 * 16 + b_glob) * 256 + n) * 4);
      if ((t & 31) == 31) __threadfence();  // flush gall to LLC before publish
      bar_lds();                            // pq[par^1] published for next step
      if ((t & 31) == 31 && tid == 0) st32_cohere(&prog[g], (u32)(t + 1));
    }
  } else {
    // =========== WORKER ROLE ===========
    const int wid = blockIdx.x - 8;
    u16* As = (u16*)smem;                 // 32x40 u16
    u16* Bs = (u16*)(smem + 2560);        // 320x40 u16
    u16* embS = (u16*)(smem + 28160);     // 32xEMBS_ST u16
    const u16* Eb = (const u16*)(ws + OFF_EB);
    const u16* Wxb = (const u16*)(ws + OFF_WXB);
    u16* gates = (u16*)(ws + OFF_GATES);
    const u16* gall = (const u16*)(ws + OFF_GALL);
    const u16* Wob = (const u16*)(ws + OFF_WOUTB);

    // ---- Phase A: emb+gates per (b, tc) item; emb lives only in LDS
    for (int it = wid; it < 256; it += NWRK) {
      const int tc = it >> 4, b = it & 15;
      const int m0x = b * T + tc * 32;
      f32x4 acc[5];
#pragma unroll
      for (int j = 0; j < 5; j++) acc[j] = (f32x4){0.f, 0.f, 0.f, 0.f};
      const int ar = tid >> 3, ak = (tid & 7) * 4;  // x staging ids (tid<256)
      f32x4 xv0, xv1;
      u32x4 ev0[3], ev1[3];

#define WEMB_ISSUE(SFX, KS)                                                       \
  do {                                                                            \
    int k0_ = (KS) * 32;                                                          \
    if (tid < 256) {                                                              \
      size_t base_ = (size_t)(m0x + ar) * V + k0_ + ak;                           \
      if (k0_ + ak + 3 < V) {                                                     \
        xv##SFX = *(const f32x4*)(x + base_);                                     \
      } else {                                                                    \
        f32x4 t_;                                                                 \
        t_[0] = (k0_ + ak + 0 < V) ? x[base_ + 0] : 0.f;                          \
        t_[1] = (k0_ + ak + 1 < V) ? x[base_ + 1] : 0.f;                          \
        t_[2] = (k0_ + ak + 2 < V) ? x[base_ + 2] : 0.f;                          \
        t_[3] = (k0_ + ak + 3 < V) ? x[base_ + 3] : 0.f;                          \
        xv##SFX = t_;                                                             \
      }                                                                           \
    }                                                                             \
    _Pragma("unroll") for (int p_ = 0; p_ < 3; p_++) {                            \
      int cc_ = tid + 512 * p_;                                                   \
      if (cc_ < 1280) {                                                           \
        int n_ = cc_ >> 2, ko_ = (cc_ & 3) * 8;                                   \
        ev##SFX[p_] = *(const u32x4*)(Eb + (size_t)n_ * KP + k0_ + ko_);          \
      }                                                                           \
    }                                                                             \
  } while (0)

#define WEMB_WRITE(SFX)                                                           \
  do {                                                                            \
    if (tid < 256) {                                                              \
      union { u16 u[4]; u32x2 v; } ua_;                                           \
      ua_.u[0] = f2bf(xv##SFX[0]); ua_.u[1] = f2bf(xv##SFX[1]);                   \
      ua_.u[2] = f2bf(xv##SFX[2]); ua_.u[3] = f2bf(xv##SFX[3]);                   \
      *(u32x2*)&As[ar * 40 + ak] = ua_.v;                                         \
    }                                                                             \
    _Pragma("unroll") for (int p_ = 0; p_ < 3; p_++) {                            \
      int cc_ = tid + 512 * p_;                                                   \
      if (cc_ < 1280) {                                                           \
        int n_ = cc_ >> 2, ko_ = (cc_ & 3) * 8;                                   \
        *(u32x4*)&Bs[n_ * 40 + ko_] = ev##SFX[p_];                                \
      }                                                                           \
    }                                                                             \
  } while (0)

      const int mt = wv & 1, ntb = (wv >> 1) * 5;
      auto wemb_compute = [&]() {
        u32x4 a = *(const u32x4*)&As[(mt * 16 + l15) * 40 + lc * 8];
#pragma unroll
        for (int j = 0; j < 5; j++) {
          u32x4 bb = *(const u32x4*)&Bs[((ntb + j) * 16 + l15) * 40 + lc * 8];
          acc[j] = MFMA(a, bb, acc[j]);
        }
      };

      constexpr int NK = 157;
      WEMB_ISSUE(0, 0);
      WEMB_ISSUE(1, 1);
      for (int ks = 0; ks < NK; ks += 2) {
        __syncthreads();
        WEMB_WRITE(0);
        if (ks + 2 < NK) WEMB_ISSUE(0, ks + 2);
        __syncthreads();
        wemb_compute();
        if (ks + 1 < NK) {
          __syncthreads();
          WEMB_WRITE(1);
          if (ks + 3 < NK) WEMB_ISSUE(1, ks + 3);
          __syncthreads();
          wemb_compute();
        }
      }
#undef WEMB_ISSUE
#undef WEMB_WRITE
      // emb -> embS (bf16)
      __syncthreads();
#pragma unroll
      for (int j = 0; j < 5; j++) {
        int nn = (ntb + j) * 16 + l15;
#pragma unroll
        for (int r = 0; r < 4; r++)
          embS[(mt * 16 + lc * 4 + r) * EMBS_ST + nn] = f2bf(acc[j][r]);
      }
      __syncthreads();

      // gates: 32m x 1024n, K=320 from embS; B direct from Wxb (L2-hot)
      const int amt = wv & 1, ngrp = wv >> 1;
      f32x4 gacc[16];
#pragma unroll
      for (int j = 0; j < 16; j++) gacc[j] = (f32x4){0.f, 0.f, 0.f, 0.f};
#pragma unroll 1
      for (int kc = 0; kc < 10; kc++) {
        u32x4 a = *(const u32x4*)&embS[(amt * 16 + l15) * EMBS_ST + kc * 32 + lc * 8];
#pragma unroll
        for (int nt = 0; nt < 16; nt++) {
          int col = ngrp * 256 + nt * 16 + l15;
          u32x4 bb = *(const u32x4*)(Wxb + (size_t)col * DP + kc * 32 + lc * 8);
          gacc[nt] = MFMA(a, bb, gacc[nt]);
        }
      }
#pragma unroll
      for (int nt = 0; nt < 16; nt++) {
#pragma unroll
        for (int r = 0; r < 4; r++) {
          int t = tc * 32 + amt * 16 + lc * 4 + r;
          int col = ngrp * 256 + nt * 16 + l15;
          int q = col >> 8, nn = col & 255;
          gates[(((size_t)t * 16 + b) * 256 + nn) * 4 + q] = f2bf(gacc[nt][r]);
        }
      }
      __threadfence();
      __syncthreads();
      if (tid == 0) atomicAdd(&flag[tc], 1u);
    }

    // ---- Phase B: out tiles gated on scan progress. idx order = tk-major.
    for (int it = wid; it < 2560; it += NWRK) {
      const int tk = it / 320, rem = it % 320;
      const int b = rem / 20, nb = rem % 20;
      const int g = b >> 1;
      const u32 need = (u32)((tk + 1) * 64);
      if (tid == 0) {
        while (ld32_cohere(&prog[g]) < need) __builtin_amdgcn_s_sleep(8);
      }
      __syncthreads();

      const int amt = wv & 3, nh = wv >> 2;
      const int m0 = b * T + tk * 64, n0 = nb * 256 + nh * 128;
      f32x4 acc[8];
#pragma unroll
      for (int j = 0; j < 8; j++) acc[j] = (f32x4){0.f, 0.f, 0.f, 0.f};
#pragma unroll 1
      for (int ks = 0; ks < 8; ks++) {
        u32x4 a = ld16_cohere((const char*)gall +
                              2 * ((size_t)(m0 + amt * 16 + l15) * H + ks * 32 + lc * 8));
#pragma unroll
        for (int nt = 0; nt < 8; nt++) {
          u32x4 bb = *(const u32x4*)(Wob + (size_t)(n0 + nt * 16 + l15) * H + ks * 32 + lc * 8);
          acc[nt] = MFMA(a, bb, acc[nt]);
        }
      }
#pragma unroll
      for (int nt = 0; nt < 8; nt++) {
        int vcol = n0 + nt * 16 + l15;
        if (vcol < V) {
#pragma unroll
          for (int r = 0; r < 4; r++) {
            int m = m0 + amt * 16 + lc * 4 + r;
            out[(size_t)m * V + vcol] = acc[nt][r];
          }
        }
      }
    }
  }
}

extern "C" void kernel_launch(void* const* d_in, const int* in_sizes, int n_in,
                              void* d_out, int out_size, void* d_ws, size_t ws_size,
                              hipStream_t stream) {
  (void)in_sizes; (void)n_in; (void)out_size; (void)ws_size;  // needs ~28 MB of ws
  const float* x      = (const float*)d_in[0];
  const float* hidden = (const float*)d_in[1];
  const float* ctx    = (const float*)d_in[2];
  const float* E      = (const float*)d_in[3];
  const float* Wf     = (const float*)d_in[4];
  const float* Uf     = (const float*)d_in[5];
  const float* Wg     = (const float*)d_in[6];
  const float* Ug     = (const float*)d_in[7];
  const float* Wi     = (const float*)d_in[8];
  const float* Ui     = (const float*)d_in[9];
  const float* Wo     = (const float*)d_in[10];
  const float* Uo     = (const float*)d_in[11];
  const float* Wout   = (const float*)d_in[12];
  char* ws = (char*)d_ws;
  float* out = (float*)d_out;

  hipLaunchKernelGGL(k_prep, dim3(1024), dim3(256), 0, stream,
                     E, Wf, Wg, Wi, Wo, Wout, ws);
  hipLaunchKernelGGL(k_prep_u, dim3(256), dim3(256), 0, stream, Uf, Ug, Ui, Uo, ws);
  hipLaunchKernelGGL(k_fused, dim3(8 + NWRK), dim3(512), 0, stream,
                     x, hidden, ctx, ws, out);
}

// Round 9
// 822.622 us; speedup vs baseline: 1.1382x; 1.1382x over previous
//
#include <hip/hip_runtime.h>
#include <stdint.h>

typedef unsigned short u16;
typedef unsigned int u32;
typedef __attribute__((ext_vector_type(8))) __bf16 bf16x8;
typedef __attribute__((ext_vector_type(4))) float f32x4;
typedef __attribute__((ext_vector_type(4))) u32 u32x4;
typedef __attribute__((ext_vector_type(2))) u32 u32x2;
typedef __attribute__((ext_vector_type(4))) int i32x4;

#define DEV __device__ __forceinline__

constexpr int V = 5000, D = 300, H = 256, BB = 16, T = 512;
constexpr int M = BB * T;      // 8192
constexpr int DP = 320;        // D padded
constexpr int KP = 5024;       // V padded (E k-dim)
constexpr int G4 = 1024;       // 4H
constexpr int NPAD = 5120;     // V padded (out n-dim)

// workspace layout (bytes). ~28 MB.
constexpr size_t OFF_EB    = 0;                                   // bf16 [DP][KP]
constexpr size_t OFF_WXB   = OFF_EB    + (size_t)DP * KP * 2;     // bf16 [G4][DP]
constexpr size_t OFF_UHB   = OFF_WXB   + (size_t)G4 * DP * 2;     // i8 qU [G4][H] + f32 zsc[G4]
constexpr size_t OFF_WOUTB = OFF_UHB   + (size_t)G4 * H * 2;      // bf16 [NPAD][H]
constexpr size_t OFF_GATES = OFF_WOUTB + (size_t)NPAD * H * 2;    // bf16 [T][B][256][4]
constexpr size_t OFF_GALL  = OFF_GATES + (size_t)T * BB * G4 * 2; // bf16 [M][H]

DEV u16 f2bf(float f) {
  u32 i = __builtin_bit_cast(u32, f);
  return (u16)((i + 0x7FFFu + ((i >> 16) & 1u)) >> 16);
}
DEV float bf2f(u16 u) { return __builtin_bit_cast(float, (u32)u << 16); }
DEV f32x4 MFMA(u32x4 a, u32x4 b, f32x4 c) {
  return __builtin_amdgcn_mfma_f32_16x16x32_bf16(
      __builtin_bit_cast(bf16x8, a), __builtin_bit_cast(bf16x8, b), c, 0, 0, 0);
}
DEV i32x4 MFMA8(u32x4 a, u32x4 b, i32x4 c) {
  return __builtin_amdgcn_mfma_i32_16x16x64_i8(
      __builtin_bit_cast(i32x4, a), __builtin_bit_cast(i32x4, b), c, 0, 0, 0);
}
DEV float sigm(float x) { return 1.f / (1.f + __expf(-x)); }
DEV float tanh_s(float x) { float e = __expf(2.f * x); return 1.f - 2.f / (e + 1.f); }

DEV void bar_lds() {
  asm volatile("s_waitcnt lgkmcnt(0)" ::: "memory");
  __builtin_amdgcn_sched_barrier(0);
  __builtin_amdgcn_s_barrier();
  __builtin_amdgcn_sched_barrier(0);
}

// ---------------- K0: weight prep. blocks 0..1023: bf16 conversions; 1024..1279: Uh->i8
__global__ __launch_bounds__(256) void k_prep(
    const float* __restrict__ E, const float* __restrict__ Wf, const float* __restrict__ Wg,
    const float* __restrict__ Wi, const float* __restrict__ Wo,
    const float* __restrict__ Uf, const float* __restrict__ Ug,
    const float* __restrict__ Ui, const float* __restrict__ Uo,
    const float* __restrict__ Wout, char* __restrict__ ws) {
  if (blockIdx.x >= 1024) {  // Uh -> int8 (per-row scale), one wave per row
    char* qU = ws + OFF_UHB;
    float* zsc = (float*)(ws + OFF_UHB + (size_t)G4 * H);
    const int row = (blockIdx.x - 1024) * 4 + (threadIdx.x >> 6);
    const int lane = threadIdx.x & 63;
    const float* Up = (row < 256) ? Uf : (row < 512) ? Ug : (row < 768) ? Ui : Uo;
    f32x4 v = *(const f32x4*)(Up + (size_t)(row & 255) * H + lane * 4);
    float m = fmaxf(fmaxf(fabsf(v[0]), fabsf(v[1])), fmaxf(fabsf(v[2]), fabsf(v[3])));
    for (int i = 1; i < 64; i <<= 1) m = fmaxf(m, __shfl_xor(m, i));
    float inv = (m > 0.f) ? 127.f / m : 0.f;
    int q0 = (int)rintf(v[0] * inv), q1 = (int)rintf(v[1] * inv);
    int q2 = (int)rintf(v[2] * inv), q3 = (int)rintf(v[3] * inv);
    q0 = max(-127, min(127, q0)); q1 = max(-127, min(127, q1));
    q2 = max(-127, min(127, q2)); q3 = max(-127, min(127, q3));
    u32 pk = (u32)(q0 & 255) | ((u32)(q1 & 255) << 8) | ((u32)(q2 & 255) << 16) |
             ((u32)(q3 & 255) << 24);
    *(u32*)(qU + (size_t)row * H + lane * 4) = pk;
    if (lane == 0) zsc[row] = m / 16129.f;  // s_n / 127^2
    return;
  }
  u16* Eb = (u16*)(ws + OFF_EB);
  u16* Wxb = (u16*)(ws + OFF_WXB);
  u16* Wob = (u16*)(ws + OFF_WOUTB);
  const int NE = DP * KP, NW = G4 * DP, NWO = NPAD * H;
  const int total = NE + NW + NWO;
  for (int i = blockIdx.x * blockDim.x + threadIdx.x; i < total; i += 1024 * blockDim.x) {
    int j = i;
    if (j < NE) {
      int nn = j / KP, k = j % KP;
      Eb[j] = f2bf((nn < D && k < V) ? E[(size_t)nn * V + k] : 0.f);
      continue;
    }
    j -= NE;
    if (j < NW) {
      int r = j / DP, k = j % DP;
      const float* Wp = (r < 256) ? Wf : (r < 512) ? Wg : (r < 768) ? Wi : Wo;
      Wxb[j] = f2bf((k < D) ? Wp[(size_t)(r & 255) * D + k] : 0.f);
      continue;
    }
    j -= NW;
    if (j < NWO) {
      int nn = j / H, k = j % H;
      Wob[j] = f2bf((nn < V) ? Wout[(size_t)nn * H + k] : 0.f);
      continue;
    }
  }
}

// ---------------- K1: fused emb+gates. 256 blocks x 512 thr; block = (tc, b) item.
// emb (32 rows x DP) lives only in LDS; gates written [t][b][n][4] bf16.
__global__ __launch_bounds__(512) void k_embgates(const float* __restrict__ x,
                                                  char* __restrict__ ws) {
  __shared__ __align__(16) u16 As[32 * 40];
  __shared__ __align__(16) u16 Bs[320 * 40];
  __shared__ __align__(16) u16 embS[32 * 328];
  const u16* Eb = (const u16*)(ws + OFF_EB);
  const u16* Wxb = (const u16*)(ws + OFF_WXB);
  u16* gates = (u16*)(ws + OFF_GATES);

  const int tid = threadIdx.x;
  const int lane = tid & 63, wv = tid >> 6;
  const int l15 = lane & 15, lc = lane >> 4;
  const int it = blockIdx.x;
  const int tc = it >> 4, b = it & 15;
  const int m0x = b * T + tc * 32;

  f32x4 acc[5];
#pragma unroll
  for (int j = 0; j < 5; j++) acc[j] = (f32x4){0.f, 0.f, 0.f, 0.f};
  const int ar = tid >> 3, ak = (tid & 7) * 4;  // x staging ids (tid<256)
  f32x4 xv0, xv1;
  u32x4 ev0[3], ev1[3];

#define WEMB_ISSUE(SFX, KS)                                                       \
  do {                                                                            \
    int k0_ = (KS) * 32;                                                          \
    if (tid < 256) {                                                              \
      size_t base_ = (size_t)(m0x + ar) * V + k0_ + ak;                           \
      if (k0_ + ak + 3 < V) {                                                     \
        xv##SFX = *(const f32x4*)(x + base_);                                     \
      } else {                                                                    \
        f32x4 t_;                                                                 \
        t_[0] = (k0_ + ak + 0 < V) ? x[base_ + 0] : 0.f;                          \
        t_[1] = (k0_ + ak + 1 < V) ? x[base_ + 1] : 0.f;                          \
        t_[2] = (k0_ + ak + 2 < V) ? x[base_ + 2] : 0.f;                          \
        t_[3] = (k0_ + ak + 3 < V) ? x[base_ + 3] : 0.f;                          \
        xv##SFX = t_;                                                             \
      }                                                                           \
    }                                                                             \
    _Pragma("unroll") for (int p_ = 0; p_ < 3; p_++) {                            \
      int cc_ = tid + 512 * p_;                                                   \
      if (cc_ < 1280) {                                                           \
        int n_ = cc_ >> 2, ko_ = (cc_ & 3) * 8;                                   \
        ev##SFX[p_] = *(const u32x4*)(Eb + (size_t)n_ * KP + k0_ + ko_);          \
      }                                                                           \
    }                                                                             \
  } while (0)

#define WEMB_WRITE(SFX)                                                           \
  do {                                                                            \
    if (tid < 256) {                                                              \
      union { u16 u[4]; u32x2 v; } ua_;                                           \
      ua_.u[0] = f2bf(xv##SFX[0]); ua_.u[1] = f2bf(xv##SFX[1]);                   \
      ua_.u[2] = f2bf(xv##SFX[2]); ua_.u[3] = f2bf(xv##SFX[3]);                   \
      *(u32x2*)&As[ar * 40 + ak] = ua_.v;                                         \
    }                                                                             \
    _Pragma("unroll") for (int p_ = 0; p_ < 3; p_++) {                            \
      int cc_ = tid + 512 * p_;                                                   \
      if (cc_ < 1280) {                                                           \
        int n_ = cc_ >> 2, ko_ = (cc_ & 3) * 8;                                   \
        *(u32x4*)&Bs[n_ * 40 + ko_] = ev##SFX[p_];                                \
      }                                                                           \
    }                                                                             \
  } while (0)

  const int mt = wv & 1, ntb = (wv >> 1) * 5;
  auto wemb_compute = [&]() {
    u32x4 a = *(const u32x4*)&As[(mt * 16 + l15) * 40 + lc * 8];
#pragma unroll
    for (int j = 0; j < 5; j++) {
      u32x4 bb = *(const u32x4*)&Bs[((ntb + j) * 16 + l15) * 40 + lc * 8];
      acc[j] = MFMA(a, bb, acc[j]);
    }
  };

  constexpr int NK = 157;
  WEMB_ISSUE(0, 0);
  WEMB_ISSUE(1, 1);
  for (int ks = 0; ks < NK; ks += 2) {
    __syncthreads();
    WEMB_WRITE(0);
    if (ks + 2 < NK) WEMB_ISSUE(0, ks + 2);
    __syncthreads();
    wemb_compute();
    if (ks + 1 < NK) {
      __syncthreads();
      WEMB_WRITE(1);
      if (ks + 3 < NK) WEMB_ISSUE(1, ks + 3);
      __syncthreads();
      wemb_compute();
    }
  }
#undef WEMB_ISSUE
#undef WEMB_WRITE
  __syncthreads();
#pragma unroll
  for (int j = 0; j < 5; j++) {
    int nn = (ntb + j) * 16 + l15;
#pragma unroll
    for (int r = 0; r < 4; r++)
      embS[(mt * 16 + lc * 4 + r) * 328 + nn] = f2bf(acc[j][r]);
  }
  __syncthreads();

  // gates: 32m x 1024n, K=DP from embS; B direct from Wxb (L2-hot)
  const int amt = wv & 1, ngrp = wv >> 1;
  f32x4 gacc[16];
#pragma unroll
  for (int j = 0; j < 16; j++) gacc[j] = (f32x4){0.f, 0.f, 0.f, 0.f};
#pragma unroll 1
  for (int kc = 0; kc < 10; kc++) {
    u32x4 a = *(const u32x4*)&embS[(amt * 16 + l15) * 328 + kc * 32 + lc * 8];
#pragma unroll
    for (int nt = 0; nt < 16; nt++) {
      int col = ngrp * 256 + nt * 16 + l15;
      u32x4 bb = *(const u32x4*)(Wxb + (size_t)col * DP + kc * 32 + lc * 8);
      gacc[nt] = MFMA(a, bb, gacc[nt]);
    }
  }
#pragma unroll
  for (int nt = 0; nt < 16; nt++) {
#pragma unroll
    for (int r = 0; r < 4; r++) {
      int t = tc * 32 + amt * 16 + lc * 4 + r;
      int col = ngrp * 256 + nt * 16 + l15;
      int q = col >> 8, nn = col & 255;
      gates[(((size_t)t * 16 + b) * 256 + nn) * 4 + q] = f2bf(gacc[nt][r]);
    }
  }
}

// ---------------- K2: recurrent scan (R7, unchanged). 8 WGs x 512 thr; WG g = batches {2g,2g+1}.
__global__ __launch_bounds__(512) void k_scan(const float* __restrict__ hidden,
                                              const float* __restrict__ ctx,
                                              char* __restrict__ ws) {
  const char* qU = (const char*)(ws + OFF_UHB);
  const float* zsc = (const float*)(ws + OFF_UHB + (size_t)G4 * H);
  const u16* gates = (const u16*)(ws + OFF_GATES);
  u16* gall = (u16*)(ws + OFF_GALL);

  __shared__ __align__(16) char pq[2][2][256];      // [par][b][n] int8 h
  __shared__ __align__(16) int zw[2][8][8][2][16];  // [par][wv][gg*2+j][b][r16] raw i32 z

  const int tid = threadIdx.x;
  const int lane = tid & 63, wv = tid >> 6;
  const int l15 = lane & 15, lc = lane >> 4;

  u32x4 uq[4][2][4];
#pragma unroll
  for (int gg = 0; gg < 4; gg++)
#pragma unroll
    for (int j = 0; j < 2; j++)
#pragma unroll
      for (int kt = 0; kt < 4; kt++)
        uq[gg][j][kt] = *(const u32x4*)(
            qU + (size_t)(gg * 256 + wv * 32 + j * 16 + l15) * H + kt * 64 + lc * 16);

  const int b = lane >> 5, np = lane & 31;
  const int n = wv * 32 + np;
  const int jj = (np >> 4) & 1, rr = np & 15;
  const int b_glob = blockIdx.x * 2 + b;
  float c = ctx[n];
  const float zs0 = zsc[n], zs1 = zsc[n + 256], zs2 = zsc[n + 512], zs3 = zsc[n + 768];
  u32x2 gxc = *(const u32x2*)(gates + (((size_t)0 * 16 + b_glob) * 256 + n) * 4);
  u32x2 gxn = *(const u32x2*)(gates + (((size_t)1 * 16 + b_glob) * 256 + n) * 4);

  {  // h(0): scale 4/127
    const int b0 = tid >> 8, n0i = tid & 255;
    float h0 = hidden[n0i];
    h0 = fminf(3.999f, fmaxf(-3.999f, h0));
    pq[0][b0][n0i] = (char)(int)rintf(h0 * 31.75f);
  }
  __syncthreads();

#pragma unroll 1
  for (int t = 0; t < T; ++t) {
    const int par = t & 1;
    u32x4 bfr[4];
#pragma unroll
    for (int kt = 0; kt < 4; kt++)
      bfr[kt] = *(const u32x4*)&pq[par][l15 & 1][kt * 64 + lc * 16];

    i32x4 acc[4][2];
#pragma unroll
    for (int gg = 0; gg < 4; gg++)
#pragma unroll
      for (int j = 0; j < 2; j++) {
        i32x4 a = {0, 0, 0, 0};
#pragma unroll
        for (int kt = 0; kt < 4; kt++) a = MFMA8(uq[gg][j][kt], bfr[kt], a);
        acc[gg][j] = a;
      }
    if (l15 < 2) {
#pragma unroll
      for (int gg = 0; gg < 4; gg++)
#pragma unroll
        for (int j = 0; j < 2; j++)
          *(i32x4*)&zw[par][wv][gg * 2 + j][l15][lc * 4] = acc[gg][j];
    }
    asm volatile("s_waitcnt lgkmcnt(0)" ::: "memory");
    __builtin_amdgcn_sched_barrier(0);

    const float hs = (t == 0) ? 4.f : 1.f;
    float z0 = (float)zw[par][wv][0 + jj][b][rr] * (zs0 * hs) + bf2f((u16)(gxc[0] & 0xFFFFu));
    float z1 = (float)zw[par][wv][2 + jj][b][rr] * (zs1 * hs) + bf2f((u16)(gxc[0] >> 16));
    float z2 = (float)zw[par][wv][4 + jj][b][rr] * (zs2 * hs) + bf2f((u16)(gxc[1] & 0xFFFFu));
    float z3 = (float)zw[par][wv][6 + jj][b][rr] * (zs3 * hs) + bf2f((u16)(gxc[1] >> 16));
    float fv = sigm(z0), gv = tanh_s(z1), iv = sigm(z2), ov = sigm(z3);
    c = gv * iv + c * fv;
    float hn = ov * tanh_s(c);
    gall[((size_t)b_glob * T + t) * H + n] = f2bf(gv);
    pq[par ^ 1][b][n] = (char)(int)rintf(hn * 127.f);
    gxc = gxn;
    int t2 = (t + 2 < T) ? (t + 2) : t;
    gxn = *(const u32x2*)(gates + (((size_t)t2 * 16 + b_glob) * 256 + n) * 4);
    bar_lds();
  }
}

// ---------------- K3: out = g_all @ Wout^T (BM=64, BN=256, K=H) + coalesced f32x4 stores
__global__ __launch_bounds__(256) void k_out(char* __restrict__ ws, float* __restrict__ out) {
  const u16* gall = (const u16*)(ws + OFF_GALL);
  const u16* Wob = (const u16*)(ws + OFF_WOUTB);
  __shared__ __align__(16) u16 As[64 * 40];
  __shared__ __align__(16) u16 Bs[256 * 40];
  __shared__ __align__(16) float tb[64 * 132];

  const int tid = threadIdx.x;
  const int blk = blockIdx.x;
  const int m0 = (blk / 20) * 64, n0 = (blk % 20) * 256;
  const int lane = tid & 63, wv = tid >> 6;
  const int l15 = lane & 15, lc = lane >> 4;

  f32x4 acc[16];
#pragma unroll
  for (int j = 0; j < 16; j++) acc[j] = (f32x4){0.f, 0.f, 0.f, 0.f};

  u32x4 av0, av1;
  u32x4 bv0[4], bv1[4];

#define OUT_ISSUE(SFX, KS)                                                        \
  do {                                                                            \
    int k0_ = (KS) * 32;                                                          \
    {                                                                             \
      int r_ = tid >> 2, ko_ = (tid & 3) * 8;                                     \
      av##SFX = *(const u32x4*)(gall + (size_t)(m0 + r_) * H + k0_ + ko_);        \
    }                                                                             \
    _Pragma("unroll") for (int j_ = 0; j_ < 4; j_++) {                            \
      int c_ = tid + 256 * j_;                                                    \
      int n_ = c_ >> 2, ko_ = (c_ & 3) * 8;                                       \
      bv##SFX[j_] = *(const u32x4*)(Wob + (size_t)(n0 + n_) * H + k0_ + ko_);     \
    }                                                                             \
  } while (0)

#define OUT_WRITE(SFX)                                                            \
  do {                                                                            \
    {                                                                             \
      int r_ = tid >> 2, ko_ = (tid & 3) * 8;                                     \
      *(u32x4*)&As[r_ * 40 + ko_] = av##SFX;                                      \
    }                                                                             \
    _Pragma("unroll") for (int j_ = 0; j_ < 4; j_++) {                            \
      int c_ = tid + 256 * j_;                                                    \
      int n_ = c_ >> 2, ko_ = (c_ & 3) * 8;                                       \
      *(u32x4*)&Bs[n_ * 40 + ko_] = bv##SFX[j_];                                  \
    }                                                                             \
  } while (0)

  auto out_compute = [&]() {
    u32x4 a = *(const u32x4*)&As[(wv * 16 + l15) * 40 + lc * 8];
#pragma unroll
    for (int nt = 0; nt < 16; nt++) {
      u32x4 b = *(const u32x4*)&Bs[(nt * 16 + l15) * 40 + lc * 8];
      acc[nt] = MFMA(a, b, acc[nt]);
    }
  };

  constexpr int NK = 8;  // H/32
  OUT_ISSUE(0, 0);
  OUT_ISSUE(1, 1);
  for (int ks = 0; ks < NK; ks += 2) {
    __syncthreads();
    OUT_WRITE(0);
    if (ks + 2 < NK) OUT_ISSUE(0, ks + 2);
    __syncthreads();
    out_compute();
    __syncthreads();
    OUT_WRITE(1);
    if (ks + 3 < NK) OUT_ISSUE(1, ks + 3);
    __syncthreads();
    out_compute();
  }

  // epilogue: LDS transpose in two 64x128 halves -> coalesced dwordx4 stores
#pragma unroll
  for (int h = 0; h < 2; h++) {
    __syncthreads();
#pragma unroll
    for (int nt = 0; nt < 8; nt++) {
#pragma unroll
      for (int r = 0; r < 4; r++)
        tb[(wv * 16 + lc * 4 + r) * 132 + nt * 16 + l15] = acc[h * 8 + nt][r];
    }
    __syncthreads();
#pragma unroll
    for (int cc = 0; cc < 8; cc++) {
      int idx = cc * 256 + tid;          // consecutive tid -> consecutive 16B chunks
      int row = idx >> 5, c4 = (idx & 31) * 4;
      int gcol = n0 + h * 128 + c4;      // V=5000 divisible by 4 -> chunk fully in/out
      if (gcol + 3 < V) {
        f32x4 v = *(const f32x4*)&tb[row * 132 + c4];
        *(f32x4*)&out[(size_t)(m0 + row) * V + gcol] = v;
      }
    }
  }
#undef OUT_ISSUE
#undef OUT_WRITE
}

extern "C" void kernel_launch(void* const* d_in, const int* in_sizes, int n_in,
                              void* d_out, int out_size, void* d_ws, size_t ws_size,
                              hipStream_t stream) {
  (void)in_sizes; (void)n_in; (void)out_size; (void)ws_size;  // needs ~28 MB of ws
  const float* x      = (const float*)d_in[0];
  const float* hidden = (const float*)d_in[1];
  const float* ctx    = (const float*)d_in[2];
  const float* E      = (const float*)d_in[3];
  const float* Wf     = (const float*)d_in[4];
  const float* Uf     = (const float*)d_in[5];
  const float* Wg     = (const float*)d_in[6];
  const float* Ug     = (const float*)d_in[7];
  const float* Wi     = (const float*)d_in[8];
  const float* Ui     = (const float*)d_in[9];
  const float* Wo     = (const float*)d_in[10];
  const float* Uo     = (const float*)d_in[11];
  const float* Wout   = (const float*)d_in[12];
  char* ws = (char*)d_ws;
  float* out = (float*)d_out;

  hipLaunchKernelGGL(k_prep, dim3(1280), dim3(256), 0, stream,
                     E, Wf, Wg, Wi, Wo, Uf, Ug, Ui, Uo, Wout, ws);
  hipLaunchKernelGGL(k_embgates, dim3(256), dim3(512), 0, stream, x, ws);
  hipLaunchKernelGGL(k_scan, dim3(8), dim3(512), 0, stream, hidden, ctx, ws);
  hipLaunchKernelGGL(k_out, dim3((M / 64) * 20), dim3(256), 0, stream, ws, out);
}